// Round 14
// baseline (312.591 us; speedup 1.0000x reference)
//
#include <hip/hip_runtime.h>
#include <math.h>

// Problem constants: B=1, H=W=64 (N=4096), C=768, 12 heads x hd=64.
#define NHEADS 12
#define NTOK 4096
#define LOG2E 1.44269504f

typedef __attribute__((ext_vector_type(8))) short bf8v;    // 8 x bf16
typedef __attribute__((ext_vector_type(4))) float f4v;     // 16x16 C/D frag
typedef __attribute__((ext_vector_type(16))) float f16v;   // 32x32 C/D frag

__device__ __forceinline__ unsigned short f2bf(float f) {
  unsigned int u = __float_as_uint(f);
  u += 0x7fffu + ((u >> 16) & 1u);   // RNE
  return (unsigned short)(u >> 16);
}
__device__ __forceinline__ bf8v pack8(float4 a, float4 b) {
  bf8v v;
  v[0] = (short)f2bf(a.x); v[1] = (short)f2bf(a.y);
  v[2] = (short)f2bf(a.z); v[3] = (short)f2bf(a.w);
  v[4] = (short)f2bf(b.x); v[5] = (short)f2bf(b.y);
  v[6] = (short)f2bf(b.z); v[7] = (short)f2bf(b.w);
  return v;
}
// pack two f32 (round via +0x8000) into (hi|lo) bf16 pair
__device__ __forceinline__ unsigned pkbf(float hi, float lo) {
  return __builtin_amdgcn_perm(__float_as_uint(hi) + 0x8000u,
                               __float_as_uint(lo) + 0x8000u, 0x07060302u);
}
__device__ __forceinline__ void gload_lds16(const void* g, void* l) {
  __builtin_amdgcn_global_load_lds(
      (const __attribute__((address_space(1))) void*)g,
      (__attribute__((address_space(3))) void*)l, 16, 0, 0);
}

// ---------------------------------------------------------------------------
// prep: unified x->bf16 cvt + qkv_w / proj_w transpose-cvt (one launch).
// ---------------------------------------------------------------------------
__device__ __forceinline__ void tcvt_body(
    const float* __restrict__ in, short* __restrict__ out, int R, int C,
    int bx, int by, int t, float (*Ts)[65])
{
    const int bc = bx * 64, br = by * 64;
    {
        const int r = t >> 2, c0 = (t & 3) * 16;
        const float* src = in + (size_t)(br + r) * C + bc + c0;
#pragma unroll
        for (int i = 0; i < 4; ++i) {
            float4 a = *(const float4*)(src + 4 * i);
            Ts[r][c0 + 4 * i + 0] = a.x;
            Ts[r][c0 + 4 * i + 1] = a.y;
            Ts[r][c0 + 4 * i + 2] = a.z;
            Ts[r][c0 + 4 * i + 3] = a.w;
        }
    }
    __syncthreads();
    const int c = t >> 2, r0 = (t & 3) * 16;
    short* dst = out + (size_t)(bc + c) * R + br + r0;
#pragma unroll
    for (int p = 0; p < 2; ++p) {
        bf8v v;
#pragma unroll
        for (int i = 0; i < 8; ++i) v[i] = (short)f2bf(Ts[r0 + p * 8 + i][c]);
        *(bf8v*)(dst + p * 8) = v;
    }
}

__global__ __launch_bounds__(256) void prep_kernel(
    const float* __restrict__ x, const float* __restrict__ qkvw,
    const float* __restrict__ pw, short* __restrict__ xh,
    short* __restrict__ wqkvT, short* __restrict__ pwT)
{
    __shared__ float Ts[64][65];
    const int bid = blockIdx.x, t = threadIdx.x;
    if (bid < 1536) {
        const size_t i = ((size_t)bid * 256 + t) * 8;
        float4 a = *(const float4*)(x + i);
        float4 b = *(const float4*)(x + i + 4);
        *(bf8v*)(xh + i) = pack8(a, b);
    } else if (bid < 1968) {
        const int idx = bid - 1536;
        tcvt_body(qkvw, wqkvT, 768, 2304, idx % 36, idx / 36, t, Ts);
    } else {
        const int idx = bid - 1968;
        tcvt_body(pw, pwT, 768, 768, idx % 12, idx / 12, t, Ts);
    }
}

// ---------------------------------------------------------------------------
// QKV GEMM (MFMA bf16): 128x96 tile, grid (24,32)=768 blocks (R13 form).
// ---------------------------------------------------------------------------
__global__ __launch_bounds__(256) void qkv_mfma_kernel(
    const short* __restrict__ xh, const short* __restrict__ wT,
    const float* __restrict__ bias, short* __restrict__ qbh,
    short* __restrict__ kbh, short* __restrict__ vbT)
{
    __shared__ __align__(16) short As[128 * 32];
    __shared__ __align__(16) short Bs[96 * 32];
    const int t = threadIdx.x;
    const int w = t >> 6, lane = t & 63;
    const int l15 = lane & 15, l4 = lane >> 4;
    const int wr = w >> 1, wc = w & 1;
    const int row0 = blockIdx.y * 128, col0 = blockIdx.x * 96;
    const int ldr = lane >> 2;
    const int ldk = (lane & 3) * 8;

    f4v acc[4][3] = {};
    const short* aBase = xh + (size_t)(row0 + w * 32 + ldr) * 768 + ldk;
    const short* bBase0 = wT + (size_t)(col0 + w * 16 + ldr) * 768 + ldk;
    const short* bBase1 = wT + (size_t)(col0 + 64 + w * 16 + ldr) * 768 + ldk;

    for (int kk = 0; kk < 768; kk += 32) {
        __syncthreads();
#pragma unroll
        for (int c = 0; c < 2; ++c)
            gload_lds16(aBase + (size_t)c * 16 * 768 + kk,
                        &As[(w * 32 + c * 16) * 32]);
        gload_lds16(bBase0 + kk, &Bs[(w * 16) * 32]);
        if (w < 2)
            gload_lds16(bBase1 + kk, &Bs[(64 + w * 16) * 32]);
        __syncthreads();
        bf8v af[4], bg[3];
#pragma unroll
        for (int i = 0; i < 4; ++i)
            af[i] = *(const bf8v*)&As[(wr * 64 + 16 * i + l15) * 32 + l4 * 8];
#pragma unroll
        for (int j = 0; j < 3; ++j)
            bg[j] = *(const bf8v*)&Bs[(wc * 48 + 16 * j + l15) * 32 + l4 * 8];
#pragma unroll
        for (int i = 0; i < 4; ++i)
#pragma unroll
            for (int j = 0; j < 3; ++j)
                acc[i][j] = __builtin_amdgcn_mfma_f32_16x16x32_bf16(
                    af[i], bg[j], acc[i][j], 0, 0, 0);
    }

#pragma unroll
    for (int j = 0; j < 3; ++j) {
        const int n = col0 + wc * 48 + 16 * j + l15;
        const int s = n / 768;            // block-uniform (96 | 768)
        const int rm = n - s * 768;
        const int h = rm >> 6, d = rm & 63;
        const float bv = bias[n];
        if (s == 2) {
            short* vdst = vbT + (size_t)(h * 64 + d) * NTOK;
#pragma unroll
            for (int i = 0; i < 4; ++i) {
                const int m = row0 + wr * 64 + 16 * i + l4 * 4;
                short4 pv;
                pv.x = (short)f2bf(acc[i][j][0] + bv);
                pv.y = (short)f2bf(acc[i][j][1] + bv);
                pv.z = (short)f2bf(acc[i][j][2] + bv);
                pv.w = (short)f2bf(acc[i][j][3] + bv);
                *(short4*)(vdst + m) = pv;
            }
        } else {
            short* dst = (s == 0) ? qbh : kbh;
#pragma unroll
            for (int i = 0; i < 4; ++i) {
                const int m = row0 + wr * 64 + 16 * i + l4 * 4;
#pragma unroll
                for (int r = 0; r < 4; ++r)
                    dst[((size_t)h * NTOK + m + r) * 64 + d] =
                        (short)f2bf(acc[i][j][r] + bv);
            }
        }
    }
}

// ---------------------------------------------------------------------------
// Flash attention v8: LDS-free main loop. Both MFMA operands are contiguous
// 16B runs in the global layouts (K A-frag = kbh token rows; V B-frag = vbT
// d rows), so K/V load straight into fragment registers — no staging tiles,
// ZERO main-loop barriers. Block = 128 threads = 2 independent waves, each
// owning 32 q's x all 4096 tokens (64 iters). LDS = prologue U/relHs only.
// Grid (64,12) = 768 blocks = exactly 6 waves/CU. launch_bounds(128,2):
// ~234 unified regs < 256 (R7 spill lesson; WRITE_SIZE is the sentinel).
// ---------------------------------------------------------------------------
union FlashSMem {
    float U[128][66];      // 33792 B  prologue relW table
    float relHs[64][66];   // 16896 B  main loop (written after U dead)
};

__global__ __launch_bounds__(128, 2) void flash_mfma_kernel(
    const short* __restrict__ qbh, const short* __restrict__ kbh,
    const short* __restrict__ vbT, const float* __restrict__ rpw,
    const float* __restrict__ rph, short* __restrict__ aob)
{
    __shared__ __align__(16) FlashSMem sm;

    const int t = threadIdx.x;
    const int qt = blockIdx.x, head = blockIdx.y;
    const int row0 = qt * 64;
    const int lane = t & 63, qh2 = t >> 6;   // wave = q-half
    const int l31 = lane & 31, hf = lane >> 5;
    const size_t hB = (size_t)head * NTOK * 64;
    const float SC = 0.125f * LOG2E;

    // Q as 32x32 B-fragments: B[k=d][n=q], lane n=l31, k = 8*hf + j
    const int q = row0 + qh2 * 32 + l31;
    bf8v bQ[4];
    {
        const short* qsrc = qbh + hB + (size_t)q * 64;
#pragma unroll
        for (int ks = 0; ks < 4; ++ks)
            bQ[ks] = *(const bf8v*)(qsrc + ks * 16 + hf * 8);
    }

    // --- fused relW: U[j][qw] = sum_d rpw[j][d] Q[qw][d]; each wave does all
    // 4 j-tiles for its 32 q's. Row j=127 never gathered -> clamp to 0.
#pragma unroll
    for (int jt = 0; jt < 4; ++jt) {
        int j = jt * 32 + l31;
        if (j > 126) j = 0;
        const float* asrc = rpw + (size_t)j * 64;
        f16v c = {};
#pragma unroll
        for (int ks = 0; ks < 4; ++ks) {
            float4 u0 = *(const float4*)(asrc + ks * 16 + hf * 8);
            float4 u1 = *(const float4*)(asrc + ks * 16 + hf * 8 + 4);
            c = __builtin_amdgcn_mfma_f32_32x32x16_bf16(
                pack8(u0, u1), bQ[ks], c, 0, 0, 0);
        }
#pragma unroll
        for (int reg = 0; reg < 16; ++reg)
            sm.U[jt * 32 + (reg & 3) + 8 * (reg >> 2) + 4 * hf]
                [qh2 * 32 + l31] = c[reg];
    }
    __syncthreads();
    // gather relW into packed-bf16 registers (LOG2E-scaled)
    const int qw = qh2 * 32 + l31;
    uint2 rwp[2][4];
#pragma unroll
    for (int t32 = 0; t32 < 2; ++t32)
#pragma unroll
        for (int g = 0; g < 4; ++g) {
            const int kw = t32 * 32 + 8 * g + 4 * hf;
            const float v0 = sm.U[qw + 63 - kw][qw] * LOG2E;
            const float v1 = sm.U[qw + 62 - kw][qw] * LOG2E;
            const float v2 = sm.U[qw + 61 - kw][qw] * LOG2E;
            const float v3 = sm.U[qw + 60 - kw][qw] * LOG2E;
            rwp[t32][g].x = pkbf(v1, v0);
            rwp[t32][g].y = pkbf(v3, v2);
        }
    __syncthreads();   // U reads done before relHs overlay writes

    // --- fused relH: relHs[kh][q] = LOG2E * (rph[qt+63-kh] . Q[q]);
    // each wave covers both kh-tiles for its own q's.
#pragma unroll
    for (int kt = 0; kt < 2; ++kt) {
        const int kh = kt * 32 + l31;
        const float* asrc = rph + (size_t)(qt + 63 - kh) * 64;
        f16v c = {};
#pragma unroll
        for (int ks = 0; ks < 4; ++ks) {
            float4 u0 = *(const float4*)(asrc + ks * 16 + hf * 8);
            float4 u1 = *(const float4*)(asrc + ks * 16 + hf * 8 + 4);
            u0.x *= LOG2E; u0.y *= LOG2E; u0.z *= LOG2E; u0.w *= LOG2E;
            u1.x *= LOG2E; u1.y *= LOG2E; u1.z *= LOG2E; u1.w *= LOG2E;
            c = __builtin_amdgcn_mfma_f32_32x32x16_bf16(
                pack8(u0, u1), bQ[ks], c, 0, 0, 0);
        }
#pragma unroll
        for (int reg = 0; reg < 16; ++reg)
            sm.relHs[kt * 32 + (reg & 3) + 8 * (reg >> 2) + 4 * hf]
                    [qh2 * 32 + l31] = c[reg];
    }
    __syncthreads();   // relHs visible; NO barriers from here on

    // direct-from-global fragment bases
    const short* kbase = kbh + hB + (size_t)l31 * 64 + hf * 8;
    const short* vbase = vbT + ((size_t)head * 64 + l31) * NTOK + hf * 8;

    // preload iter-0 K A-frags: frag(t32,ks) = tokens t32*32+l31, d=ks*16+
    bf8v kA[2][4];
#pragma unroll
    for (int t32 = 0; t32 < 2; ++t32)
#pragma unroll
        for (int ks = 0; ks < 4; ++ks)
            kA[t32][ks] = *(const bf8v*)(kbase + (size_t)(t32 * 32) * 64 +
                                         ks * 16);

    f16v O[2] = {{}, {}};   // rows=q (C layout), col d = nt*32+l31
    float lsum = 0.f;

    for (int it = 0; it < 64; ++it) {
        // V B-frags for this iter (issued early; used after softmax)
        bf8v vB[2][2][2];   // [t32][ks2][nt]
#pragma unroll
        for (int nt = 0; nt < 2; ++nt)
#pragma unroll
            for (int t32 = 0; t32 < 2; ++t32)
#pragma unroll
                for (int ks2 = 0; ks2 < 2; ++ks2)
                    vB[t32][ks2][nt] = *(const bf8v*)(
                        vbase + (size_t)nt * 32 * NTOK + it * 64 + t32 * 32 +
                        ks2 * 16);

        // S^T: A = K token rows (prefetched), B = bQ
        f16v acc[2] = {{}, {}};
#pragma unroll
        for (int ks = 0; ks < 4; ++ks)
#pragma unroll
            for (int t32 = 0; t32 < 2; ++t32)
                acc[t32] = __builtin_amdgcn_mfma_f32_32x32x16_bf16(
                    kA[t32][ks], bQ[ks], acc[t32], 0, 0, 0);

        // prefetch next iter's K A-frags
        bf8v kN[2][4];
        {
            const int itn = (it < 63) ? it + 1 : 63;
#pragma unroll
            for (int t32 = 0; t32 < 2; ++t32)
#pragma unroll
                for (int ks = 0; ks < 4; ++ks)
                    kN[t32][ks] = *(const bf8v*)(
                        kbase + (size_t)(itn * 64 + t32 * 32) * 64 + ks * 16);
        }

        const float rh = sm.relHs[it][qh2 * 32 + l31];

        // e = exp2(SC*acc + rw + rh); pack to bf16 pairs per 4-row group
        unsigned xg[2][4], yg[2][4];
#pragma unroll
        for (int t32 = 0; t32 < 2; ++t32) {
            float sub = 0.f;
#pragma unroll
            for (int g = 0; g < 4; ++g) {
                const unsigned u0 = rwp[t32][g].x;
                const unsigned u1 = rwp[t32][g].y;
                const float b0 = __uint_as_float(u0 << 16) + rh;
                const float b1 = __uint_as_float(u0 & 0xffff0000u) + rh;
                const float b2 = __uint_as_float(u1 << 16) + rh;
                const float b3 = __uint_as_float(u1 & 0xffff0000u) + rh;
                const float e0 = __builtin_amdgcn_exp2f(
                    fmaf(acc[t32][4 * g + 0], SC, b0));
                const float e1 = __builtin_amdgcn_exp2f(
                    fmaf(acc[t32][4 * g + 1], SC, b1));
                const float e2 = __builtin_amdgcn_exp2f(
                    fmaf(acc[t32][4 * g + 2], SC, b2));
                const float e3 = __builtin_amdgcn_exp2f(
                    fmaf(acc[t32][4 * g + 3], SC, b3));
                sub += (e0 + e1) + (e2 + e3);
                xg[t32][g] = pkbf(e1, e0);
                yg[t32][g] = pkbf(e3, e2);
            }
            lsum += sub;
        }

        // PV: A-frag via permlane32_swap pairs; B = direct-loaded V frags
#pragma unroll
        for (int t32 = 0; t32 < 2; ++t32)
#pragma unroll
            for (int ks2 = 0; ks2 < 2; ++ks2) {
                auto px = __builtin_amdgcn_permlane32_swap(
                    xg[t32][2 * ks2], xg[t32][2 * ks2 + 1], false, false);
                auto py = __builtin_amdgcn_permlane32_swap(
                    yg[t32][2 * ks2], yg[t32][2 * ks2 + 1], false, false);
                int4 av;
                av.x = (int)px[0];
                av.y = (int)py[0];
                av.z = (int)px[1];
                av.w = (int)py[1];
                union { int4 i; bf8v v; } u; u.i = av;
#pragma unroll
                for (int nt = 0; nt < 2; ++nt)
                    O[nt] = __builtin_amdgcn_mfma_f32_32x32x16_bf16(
                        u.v, vB[t32][ks2][nt], O[nt], 0, 0, 0);
            }

#pragma unroll
        for (int t32 = 0; t32 < 2; ++t32)
#pragma unroll
            for (int ks = 0; ks < 4; ++ks)
                kA[t32][ks] = kN[t32][ks];
    }

    // epilogue: hf-pair reduce of l, normalize, store (no cross-wave combine)
    lsum += __shfl_xor(lsum, 32);
    const float linv = 1.0f / lsum;   // valid for q = l31 on all lanes
#pragma unroll
    for (int nt = 0; nt < 2; ++nt)
#pragma unroll
        for (int reg = 0; reg < 16; ++reg) {
            const int qr = (reg & 3) + 8 * (reg >> 2) + 4 * hf;
            const float li = __shfl(linv, qr);
            aob[(size_t)(row0 + qh2 * 32 + qr) * 768 + head * 64 + nt * 32 +
                l31] = (short)f2bf(O[nt][reg] * li);
        }
}

// ---------------------------------------------------------------------------
// proj GEMM (MFMA bf16), 64x128 tile -> 384 blocks.
// ---------------------------------------------------------------------------
__global__ __launch_bounds__(256) void proj_mfma_kernel(
    const short* __restrict__ aoh, const short* __restrict__ pwT,
    const float* __restrict__ bias, float* __restrict__ out)
{
    __shared__ __align__(16) short As[64 * 32];
    __shared__ __align__(16) short Bs[128 * 32];
    const int t = threadIdx.x;
    const int w = t >> 6, lane = t & 63;
    const int l15 = lane & 15, l4 = lane >> 4;
    const int wr = w >> 1, wc = w & 1;
    const int row0 = blockIdx.y * 64, col0 = blockIdx.x * 128;
    const int ldr = lane >> 2;
    const int ldk = (lane & 3) * 8;

    f4v acc[2][4] = {};
    const short* aBase = aoh + (size_t)(row0 + w * 16 + ldr) * 768 + ldk;
    const short* bBase = pwT + (size_t)(col0 + w * 32 + ldr) * 768 + ldk;

    for (int kk = 0; kk < 768; kk += 32) {
        __syncthreads();
        gload_lds16(aBase + kk, &As[(w * 16) * 32]);
#pragma unroll
        for (int c = 0; c < 2; ++c)
            gload_lds16(bBase + (size_t)c * 16 * 768 + kk,
                        &Bs[(w * 32 + c * 16) * 32]);
        __syncthreads();
        bf8v af[2], bg[4];
#pragma unroll
        for (int i = 0; i < 2; ++i)
            af[i] = *(const bf8v*)&As[(wr * 32 + 16 * i + l15) * 32 + l4 * 8];
#pragma unroll
        for (int j = 0; j < 4; ++j)
            bg[j] = *(const bf8v*)&Bs[(wc * 64 + 16 * j + l15) * 32 + l4 * 8];
#pragma unroll
        for (int i = 0; i < 2; ++i)
#pragma unroll
            for (int j = 0; j < 4; ++j)
                acc[i][j] = __builtin_amdgcn_mfma_f32_16x16x32_bf16(
                    af[i], bg[j], acc[i][j], 0, 0, 0);
    }

#pragma unroll
    for (int j = 0; j < 4; ++j) {
        const int n = col0 + wc * 64 + 16 * j + l15;
        const float bv = bias[n];
#pragma unroll
        for (int i = 0; i < 2; ++i) {
            const int m = row0 + wr * 32 + 16 * i + l4 * 4;
#pragma unroll
            for (int r = 0; r < 4; ++r)
                out[(size_t)(m + r) * 768 + n] = acc[i][j][r] + bv;
        }
    }
}

// ---------------------------------------------------------------------------
extern "C" void kernel_launch(void* const* d_in, const int* in_sizes, int n_in,
                              void* d_out, int out_size, void* d_ws,
                              size_t ws_size, hipStream_t stream)
{
    (void)in_sizes; (void)n_in; (void)out_size; (void)ws_size;
    const float* x    = (const float*)d_in[0];
    const float* qkvw = (const float*)d_in[1];
    const float* qkvb = (const float*)d_in[2];
    const float* pw   = (const float*)d_in[3];
    const float* pb   = (const float*)d_in[4];
    const float* rph  = (const float*)d_in[5];
    const float* rpw  = (const float*)d_in[6];
    float* out = (float*)d_out;

    const size_t S = (size_t)NHEADS * NTOK * 64;  // 3,145,728 (= 4096*768)
    short* qbh  = (short*)d_ws;          // S bf16   q  [h][tok][d]
    short* kbh  = qbh + S;               // S bf16   k  [h][tok][d]
    short* vbT  = kbh + S;               // S bf16   v^T [h][d][tok]
    short* xh   = vbT + S;               // S bf16   x [tok][c]; dead after
    short* aob  = xh;                    //   qkv -> aliased as attn out
    short* wqkvT = xh + S;               // 2304*768 bf16
    short* pwT  = wqkvT + (size_t)2304 * 768;  // 768*768 bf16
    // total ~29.6 MB

    prep_kernel<<<dim3(2112), 256, 0, stream>>>(x, qkvw, pw, xh, wqkvT, pwT);
    qkv_mfma_kernel<<<dim3(24, 32), 256, 0, stream>>>(xh, wqkvT, qkvb,
                                                      qbh, kbh, vbT);
    flash_mfma_kernel<<<dim3(64, NHEADS), 128, 0, stream>>>(qbh, kbh, vbT,
                                                            rpw, rph, aob);
    proj_mfma_kernel<<<dim3(6, 64), 256, 0, stream>>>(aob, pwT, pb, out);
}

// Round 15
// 262.658 us; speedup vs baseline: 1.1901x; 1.1901x over previous
//
#include <hip/hip_runtime.h>
#include <math.h>

// Problem constants: B=1, H=W=64 (N=4096), C=768, 12 heads x hd=64.
#define NHEADS 12
#define NTOK 4096
#define LOG2E 1.44269504f

typedef __attribute__((ext_vector_type(8))) short bf8v;    // 8 x bf16
typedef __attribute__((ext_vector_type(4))) float f4v;     // 16x16 C/D frag
typedef __attribute__((ext_vector_type(16))) float f16v;   // 32x32 C/D frag

__device__ __forceinline__ unsigned short f2bf(float f) {
  unsigned int u = __float_as_uint(f);
  u += 0x7fffu + ((u >> 16) & 1u);   // RNE
  return (unsigned short)(u >> 16);
}
__device__ __forceinline__ bf8v pack8(float4 a, float4 b) {
  bf8v v;
  v[0] = (short)f2bf(a.x); v[1] = (short)f2bf(a.y);
  v[2] = (short)f2bf(a.z); v[3] = (short)f2bf(a.w);
  v[4] = (short)f2bf(b.x); v[5] = (short)f2bf(b.y);
  v[6] = (short)f2bf(b.z); v[7] = (short)f2bf(b.w);
  return v;
}
// pack two f32 (round via +0x8000) into (hi|lo) bf16 pair
__device__ __forceinline__ unsigned pkbf(float hi, float lo) {
  return __builtin_amdgcn_perm(__float_as_uint(hi) + 0x8000u,
                               __float_as_uint(lo) + 0x8000u, 0x07060302u);
}
__device__ __forceinline__ void gload_lds16(const void* g, void* l) {
  __builtin_amdgcn_global_load_lds(
      (const __attribute__((address_space(1))) void*)g,
      (__attribute__((address_space(3))) void*)l, 16, 0, 0);
}

// ---------------------------------------------------------------------------
// prep: unified x->bf16 cvt + qkv_w / proj_w transpose-cvt (one launch).
// ---------------------------------------------------------------------------
__device__ __forceinline__ void tcvt_body(
    const float* __restrict__ in, short* __restrict__ out, int R, int C,
    int bx, int by, int t, float (*Ts)[65])
{
    const int bc = bx * 64, br = by * 64;
    {
        const int r = t >> 2, c0 = (t & 3) * 16;
        const float* src = in + (size_t)(br + r) * C + bc + c0;
#pragma unroll
        for (int i = 0; i < 4; ++i) {
            float4 a = *(const float4*)(src + 4 * i);
            Ts[r][c0 + 4 * i + 0] = a.x;
            Ts[r][c0 + 4 * i + 1] = a.y;
            Ts[r][c0 + 4 * i + 2] = a.z;
            Ts[r][c0 + 4 * i + 3] = a.w;
        }
    }
    __syncthreads();
    const int c = t >> 2, r0 = (t & 3) * 16;
    short* dst = out + (size_t)(bc + c) * R + br + r0;
#pragma unroll
    for (int p = 0; p < 2; ++p) {
        bf8v v;
#pragma unroll
        for (int i = 0; i < 8; ++i) v[i] = (short)f2bf(Ts[r0 + p * 8 + i][c]);
        *(bf8v*)(dst + p * 8) = v;
    }
}

__global__ __launch_bounds__(256) void prep_kernel(
    const float* __restrict__ x, const float* __restrict__ qkvw,
    const float* __restrict__ pw, short* __restrict__ xh,
    short* __restrict__ wqkvT, short* __restrict__ pwT)
{
    __shared__ float Ts[64][65];
    const int bid = blockIdx.x, t = threadIdx.x;
    if (bid < 1536) {
        const size_t i = ((size_t)bid * 256 + t) * 8;
        float4 a = *(const float4*)(x + i);
        float4 b = *(const float4*)(x + i + 4);
        *(bf8v*)(xh + i) = pack8(a, b);
    } else if (bid < 1968) {
        const int idx = bid - 1536;
        tcvt_body(qkvw, wqkvT, 768, 2304, idx % 36, idx / 36, t, Ts);
    } else {
        const int idx = bid - 1968;
        tcvt_body(pw, pwT, 768, 768, idx % 12, idx / 12, t, Ts);
    }
}

// ---------------------------------------------------------------------------
// QKV GEMM (MFMA bf16): 128x96 tile, grid (24,32)=768 blocks (R13 form).
// ---------------------------------------------------------------------------
__global__ __launch_bounds__(256) void qkv_mfma_kernel(
    const short* __restrict__ xh, const short* __restrict__ wT,
    const float* __restrict__ bias, short* __restrict__ qbh,
    short* __restrict__ kbh, short* __restrict__ vbT)
{
    __shared__ __align__(16) short As[128 * 32];
    __shared__ __align__(16) short Bs[96 * 32];
    const int t = threadIdx.x;
    const int w = t >> 6, lane = t & 63;
    const int l15 = lane & 15, l4 = lane >> 4;
    const int wr = w >> 1, wc = w & 1;
    const int row0 = blockIdx.y * 128, col0 = blockIdx.x * 96;
    const int ldr = lane >> 2;
    const int ldk = (lane & 3) * 8;

    f4v acc[4][3] = {};
    const short* aBase = xh + (size_t)(row0 + w * 32 + ldr) * 768 + ldk;
    const short* bBase0 = wT + (size_t)(col0 + w * 16 + ldr) * 768 + ldk;
    const short* bBase1 = wT + (size_t)(col0 + 64 + w * 16 + ldr) * 768 + ldk;

    for (int kk = 0; kk < 768; kk += 32) {
        __syncthreads();
#pragma unroll
        for (int c = 0; c < 2; ++c)
            gload_lds16(aBase + (size_t)c * 16 * 768 + kk,
                        &As[(w * 32 + c * 16) * 32]);
        gload_lds16(bBase0 + kk, &Bs[(w * 16) * 32]);
        if (w < 2)
            gload_lds16(bBase1 + kk, &Bs[(64 + w * 16) * 32]);
        __syncthreads();
        bf8v af[4], bg[3];
#pragma unroll
        for (int i = 0; i < 4; ++i)
            af[i] = *(const bf8v*)&As[(wr * 64 + 16 * i + l15) * 32 + l4 * 8];
#pragma unroll
        for (int j = 0; j < 3; ++j)
            bg[j] = *(const bf8v*)&Bs[(wc * 48 + 16 * j + l15) * 32 + l4 * 8];
#pragma unroll
        for (int i = 0; i < 4; ++i)
#pragma unroll
            for (int j = 0; j < 3; ++j)
                acc[i][j] = __builtin_amdgcn_mfma_f32_16x16x32_bf16(
                    af[i], bg[j], acc[i][j], 0, 0, 0);
    }

#pragma unroll
    for (int j = 0; j < 3; ++j) {
        const int n = col0 + wc * 48 + 16 * j + l15;
        const int s = n / 768;            // block-uniform (96 | 768)
        const int rm = n - s * 768;
        const int h = rm >> 6, d = rm & 63;
        const float bv = bias[n];
        if (s == 2) {
            short* vdst = vbT + (size_t)(h * 64 + d) * NTOK;
#pragma unroll
            for (int i = 0; i < 4; ++i) {
                const int m = row0 + wr * 64 + 16 * i + l4 * 4;
                short4 pv;
                pv.x = (short)f2bf(acc[i][j][0] + bv);
                pv.y = (short)f2bf(acc[i][j][1] + bv);
                pv.z = (short)f2bf(acc[i][j][2] + bv);
                pv.w = (short)f2bf(acc[i][j][3] + bv);
                *(short4*)(vdst + m) = pv;
            }
        } else {
            short* dst = (s == 0) ? qbh : kbh;
#pragma unroll
            for (int i = 0; i < 4; ++i) {
                const int m = row0 + wr * 64 + 16 * i + l4 * 4;
#pragma unroll
                for (int r = 0; r < 4; ++r)
                    dst[((size_t)h * NTOK + m + r) * 64 + d] =
                        (short)f2bf(acc[i][j][r] + bv);
            }
        }
    }
}

// ---------------------------------------------------------------------------
// Flash attention v9: R13 skeleton (LDS-staged K, 2 barriers/iter, 4 waves,
// 3 blocks/CU) + R14's one validated piece: V B-frags load DIRECTLY from
// global (vbT d-rows are fragment-contiguous). Deletes the Vt tile: LDS ops
// 42 -> 22 per iter, LDS 51.2 -> 34 KB. V loads issue before the barriers
// (global, no LDS dep) so their latency overlaps the barrier wait.
// ---------------------------------------------------------------------------
union FlashSMem {
    struct {
        short Ks[128][68];     // 17408 B  [tok][d], pad 4
        float relHs[64][65];   // 16640 B  [kh][q-local] (log2e)
    };
    float U[128 * 65];         // 33280 B  prologue overlay
    struct {
        float OEp[64][64];     // 16384 B  epilogue O-combine
        float lEp[64];         //   256 B  epilogue l-combine
    };
};

__global__ __launch_bounds__(256, 3) void flash_mfma_kernel(
    const short* __restrict__ qbh, const short* __restrict__ kbh,
    const short* __restrict__ vbT, const float* __restrict__ rpw,
    const float* __restrict__ rph, short* __restrict__ aob)
{
    __shared__ __align__(16) FlashSMem sm;

    const int t = threadIdx.x;
    const int qt = blockIdx.x, head = blockIdx.y;
    const int row0 = qt * 64;
    const int lane = t & 63, w = t >> 6;
    const int qh2 = w & 1, th = w >> 1;
    const int l31 = lane & 31, hf = lane >> 5;
    const size_t hB = (size_t)head * NTOK * 64;
    const float SC = 0.125f * LOG2E;

    // Q as 32x32 B-fragments: B[k=d][n=q], lane n=l31, k = 8*hf + j
    const int q = row0 + qh2 * 32 + l31;
    bf8v bQ[4];
    {
        const short* qsrc = qbh + hB + (size_t)q * 64;
#pragma unroll
        for (int ks = 0; ks < 4; ++ks)
            bQ[ks] = *(const bf8v*)(qsrc + ks * 16 + hf * 8);
    }
    // K staging pointers (R13 pattern) + direct-V fragment base (R14 piece)
    const int sx = t >> 2;            // K token row
    const int sck = (t & 3) * 16;     // K d-offset (shorts)
    const short* kptr = kbh + hB + (size_t)sx * 64 + sck;
    const short* vbase = vbT + ((size_t)head * 64 + l31) * NTOK + hf * 8;
    bf8v kpf[4];
    kpf[0] = *(const bf8v*)(kptr);
    kpf[1] = *(const bf8v*)(kptr + 8);
    kpf[2] = *(const bf8v*)(kptr + 64 * 64);
    kpf[3] = *(const bf8v*)(kptr + 64 * 64 + 8);

    // --- fused relW: U[j][qw] = sum_d rpw[j][d] Q[qw][d]; row j=127 never
    // gathered (qw+63-kw <= 126) -> clamp its load to row 0.
#pragma unroll
    for (int jt2 = 0; jt2 < 2; ++jt2) {
        const int jt = 2 * th + jt2;
        int j = jt * 32 + l31;
        if (j > 126) j = 0;
        const float* asrc = rpw + (size_t)j * 64;
        f16v c = {};
#pragma unroll
        for (int ks = 0; ks < 4; ++ks) {
            float4 u0 = *(const float4*)(asrc + ks * 16 + hf * 8);
            float4 u1 = *(const float4*)(asrc + ks * 16 + hf * 8 + 4);
            c = __builtin_amdgcn_mfma_f32_32x32x16_bf16(
                pack8(u0, u1), bQ[ks], c, 0, 0, 0);
        }
#pragma unroll
        for (int reg = 0; reg < 16; ++reg)
            sm.U[(jt * 32 + (reg & 3) + 8 * (reg >> 2) + 4 * hf) * 65 +
                 qh2 * 32 + l31] = c[reg];
    }
    __syncthreads();
    // gather relW into packed-bf16 registers (LOG2E-scaled)
    const int qw = qh2 * 32 + l31;
    uint2 rwp[2][4];
#pragma unroll
    for (int t32 = 0; t32 < 2; ++t32)
#pragma unroll
        for (int g = 0; g < 4; ++g) {
            const int kw = t32 * 32 + 8 * g + 4 * hf;
            const float v0 = sm.U[(qw + 63 - kw) * 65 + qw] * LOG2E;
            const float v1 = sm.U[(qw + 62 - kw) * 65 + qw] * LOG2E;
            const float v2 = sm.U[(qw + 61 - kw) * 65 + qw] * LOG2E;
            const float v3 = sm.U[(qw + 60 - kw) * 65 + qw] * LOG2E;
            rwp[t32][g].x = pkbf(v1, v0);
            rwp[t32][g].y = pkbf(v3, v2);
        }
    __syncthreads();   // U reads done before relHs (and Ks) overwrites

    // --- fused relH: relHs[kh][q] = LOG2E * (rph[qt+63-kh] . Q[q])
    {
        const int kh = th * 32 + l31;
        const float* asrc = rph + (size_t)(qt + 63 - kh) * 64;
        f16v c = {};
#pragma unroll
        for (int ks = 0; ks < 4; ++ks) {
            float4 u0 = *(const float4*)(asrc + ks * 16 + hf * 8);
            float4 u1 = *(const float4*)(asrc + ks * 16 + hf * 8 + 4);
            u0.x *= LOG2E; u0.y *= LOG2E; u0.z *= LOG2E; u0.w *= LOG2E;
            u1.x *= LOG2E; u1.y *= LOG2E; u1.z *= LOG2E; u1.w *= LOG2E;
            c = __builtin_amdgcn_mfma_f32_32x32x16_bf16(
                pack8(u0, u1), bQ[ks], c, 0, 0, 0);
        }
#pragma unroll
        for (int reg = 0; reg < 16; ++reg)
            sm.relHs[th * 32 + (reg & 3) + 8 * (reg >> 2) + 4 * hf]
                    [qh2 * 32 + l31] = c[reg];
    }
    // (loop-top barrier makes relHs visible before first read)

    f16v O[2] = {{}, {}};   // rows=q (C layout), col d = nt*32+l31
    float lsum = 0.f;

    for (int it = 0; it < 32; ++it) {
        // V B-frags for this iter: pure global loads, no LDS dependency —
        // issue BEFORE the barriers so latency overlaps the barrier wait.
        bf8v vB[2][2][2];   // [t32][ks2][nt]
#pragma unroll
        for (int nt = 0; nt < 2; ++nt)
#pragma unroll
            for (int t32 = 0; t32 < 2; ++t32)
#pragma unroll
                for (int ks2 = 0; ks2 < 2; ++ks2)
                    vB[t32][ks2][nt] = *(const bf8v*)(
                        vbase + (size_t)nt * 32 * NTOK + it * 128 + th * 64 +
                        t32 * 32 + ks2 * 16);

        __syncthreads();
        *(bf8v*)&sm.Ks[sx][sck] = kpf[0];
        *(bf8v*)&sm.Ks[sx][sck + 8] = kpf[1];
        *(bf8v*)&sm.Ks[sx + 64][sck] = kpf[2];
        *(bf8v*)&sm.Ks[sx + 64][sck + 8] = kpf[3];
        {
            const int itn = (it < 31) ? it + 1 : 31;
            const short* kp = kptr + (size_t)itn * 128 * 64;
            kpf[0] = *(const bf8v*)kp;
            kpf[1] = *(const bf8v*)(kp + 8);
            kpf[2] = *(const bf8v*)(kp + 64 * 64);
            kpf[3] = *(const bf8v*)(kp + 64 * 64 + 8);
        }
        __syncthreads();

        // S^T: A = K tokens (this wave's half), B = bQ
        f16v acc[2] = {{}, {}};
#pragma unroll
        for (int ks = 0; ks < 4; ++ks)
#pragma unroll
            for (int t32 = 0; t32 < 2; ++t32)
                acc[t32] = __builtin_amdgcn_mfma_f32_32x32x16_bf16(
                    *(const bf8v*)&sm.Ks[th * 64 + t32 * 32 + l31]
                                        [ks * 16 + hf * 8],
                    bQ[ks], acc[t32], 0, 0, 0);

        const float rh = sm.relHs[2 * it + th][qh2 * 32 + l31];

        // e = exp2(SC*acc + rw + rh); pack to bf16 pairs per 4-row group
        unsigned xg[2][4], yg[2][4];
#pragma unroll
        for (int t32 = 0; t32 < 2; ++t32) {
            float sub = 0.f;
#pragma unroll
            for (int g = 0; g < 4; ++g) {
                const unsigned u0 = rwp[t32][g].x;
                const unsigned u1 = rwp[t32][g].y;
                const float b0 = __uint_as_float(u0 << 16) + rh;
                const float b1 = __uint_as_float(u0 & 0xffff0000u) + rh;
                const float b2 = __uint_as_float(u1 << 16) + rh;
                const float b3 = __uint_as_float(u1 & 0xffff0000u) + rh;
                const float e0 = __builtin_amdgcn_exp2f(
                    fmaf(acc[t32][4 * g + 0], SC, b0));
                const float e1 = __builtin_amdgcn_exp2f(
                    fmaf(acc[t32][4 * g + 1], SC, b1));
                const float e2 = __builtin_amdgcn_exp2f(
                    fmaf(acc[t32][4 * g + 2], SC, b2));
                const float e3 = __builtin_amdgcn_exp2f(
                    fmaf(acc[t32][4 * g + 3], SC, b3));
                sub += (e0 + e1) + (e2 + e3);
                xg[t32][g] = pkbf(e1, e0);
                yg[t32][g] = pkbf(e3, e2);
            }
            lsum += sub;
        }

        // PV: A-frag via permlane32_swap pairs; B = direct-loaded V frags
#pragma unroll
        for (int t32 = 0; t32 < 2; ++t32)
#pragma unroll
            for (int ks2 = 0; ks2 < 2; ++ks2) {
                auto px = __builtin_amdgcn_permlane32_swap(
                    xg[t32][2 * ks2], xg[t32][2 * ks2 + 1], false, false);
                auto py = __builtin_amdgcn_permlane32_swap(
                    yg[t32][2 * ks2], yg[t32][2 * ks2 + 1], false, false);
                int4 av;
                av.x = (int)px[0];
                av.y = (int)py[0];
                av.z = (int)px[1];
                av.w = (int)py[1];
                union { int4 i; bf8v v; } u; u.i = av;
#pragma unroll
                for (int nt = 0; nt < 2; ++nt)
                    O[nt] = __builtin_amdgcn_mfma_f32_32x32x16_bf16(
                        u.v, vB[t32][ks2][nt], O[nt], 0, 0, 0);
            }
    }

    // epilogue: lanes l / l+32 share q -> reduce; then combine the two
    // token-half waves (th) via LDS union members, normalize, store.
    lsum += __shfl_xor(lsum, 32);
    __syncthreads();
    if (th == 1) {
#pragma unroll
        for (int nt = 0; nt < 2; ++nt)
#pragma unroll
            for (int reg = 0; reg < 16; ++reg) {
                const int qr = (reg & 3) + 8 * (reg >> 2) + 4 * hf;
                sm.OEp[qh2 * 32 + qr][nt * 32 + l31] = O[nt][reg];
            }
        if (lane < 32) sm.lEp[qh2 * 32 + l31] = lsum;
    }
    __syncthreads();
    if (th == 0) {
        lsum += sm.lEp[qh2 * 32 + l31];
        const float linv = 1.0f / lsum;
#pragma unroll
        for (int nt = 0; nt < 2; ++nt)
#pragma unroll
            for (int reg = 0; reg < 16; ++reg) {
                const int qr = (reg & 3) + 8 * (reg >> 2) + 4 * hf;
                const float li = __shfl(linv, qr);
                const float o =
                    O[nt][reg] + sm.OEp[qh2 * 32 + qr][nt * 32 + l31];
                aob[(size_t)(row0 + qh2 * 32 + qr) * 768 + head * 64 +
                    nt * 32 + l31] = (short)f2bf(o * li);
            }
    }
}

// ---------------------------------------------------------------------------
// proj GEMM (MFMA bf16), 64x128 tile -> 384 blocks.
// ---------------------------------------------------------------------------
__global__ __launch_bounds__(256) void proj_mfma_kernel(
    const short* __restrict__ aoh, const short* __restrict__ pwT,
    const float* __restrict__ bias, float* __restrict__ out)
{
    __shared__ __align__(16) short As[64 * 32];
    __shared__ __align__(16) short Bs[128 * 32];
    const int t = threadIdx.x;
    const int w = t >> 6, lane = t & 63;
    const int l15 = lane & 15, l4 = lane >> 4;
    const int wr = w >> 1, wc = w & 1;
    const int row0 = blockIdx.y * 64, col0 = blockIdx.x * 128;
    const int ldr = lane >> 2;
    const int ldk = (lane & 3) * 8;

    f4v acc[2][4] = {};
    const short* aBase = aoh + (size_t)(row0 + w * 16 + ldr) * 768 + ldk;
    const short* bBase = pwT + (size_t)(col0 + w * 32 + ldr) * 768 + ldk;

    for (int kk = 0; kk < 768; kk += 32) {
        __syncthreads();
        gload_lds16(aBase + kk, &As[(w * 16) * 32]);
#pragma unroll
        for (int c = 0; c < 2; ++c)
            gload_lds16(bBase + (size_t)c * 16 * 768 + kk,
                        &Bs[(w * 32 + c * 16) * 32]);
        __syncthreads();
        bf8v af[2], bg[4];
#pragma unroll
        for (int i = 0; i < 2; ++i)
            af[i] = *(const bf8v*)&As[(wr * 32 + 16 * i + l15) * 32 + l4 * 8];
#pragma unroll
        for (int j = 0; j < 4; ++j)
            bg[j] = *(const bf8v*)&Bs[(wc * 64 + 16 * j + l15) * 32 + l4 * 8];
#pragma unroll
        for (int i = 0; i < 2; ++i)
#pragma unroll
            for (int j = 0; j < 4; ++j)
                acc[i][j] = __builtin_amdgcn_mfma_f32_16x16x32_bf16(
                    af[i], bg[j], acc[i][j], 0, 0, 0);
    }

#pragma unroll
    for (int j = 0; j < 4; ++j) {
        const int n = col0 + wc * 64 + 16 * j + l15;
        const float bv = bias[n];
#pragma unroll
        for (int i = 0; i < 2; ++i) {
            const int m = row0 + wr * 32 + 16 * i + l4 * 4;
#pragma unroll
            for (int r = 0; r < 4; ++r)
                out[(size_t)(m + r) * 768 + n] = acc[i][j][r] + bv;
        }
    }
}

// ---------------------------------------------------------------------------
extern "C" void kernel_launch(void* const* d_in, const int* in_sizes, int n_in,
                              void* d_out, int out_size, void* d_ws,
                              size_t ws_size, hipStream_t stream)
{
    (void)in_sizes; (void)n_in; (void)out_size; (void)ws_size;
    const float* x    = (const float*)d_in[0];
    const float* qkvw = (const float*)d_in[1];
    const float* qkvb = (const float*)d_in[2];
    const float* pw   = (const float*)d_in[3];
    const float* pb   = (const float*)d_in[4];
    const float* rph  = (const float*)d_in[5];
    const float* rpw  = (const float*)d_in[6];
    float* out = (float*)d_out;

    const size_t S = (size_t)NHEADS * NTOK * 64;  // 3,145,728 (= 4096*768)
    short* qbh  = (short*)d_ws;          // S bf16   q  [h][tok][d]
    short* kbh  = qbh + S;               // S bf16   k  [h][tok][d]
    short* vbT  = kbh + S;               // S bf16   v^T [h][d][tok]
    short* xh   = vbT + S;               // S bf16   x [tok][c]; dead after
    short* aob  = xh;                    //   qkv -> aliased as attn out
    short* wqkvT = xh + S;               // 2304*768 bf16
    short* pwT  = wqkvT + (size_t)2304 * 768;  // 768*768 bf16
    // total ~29.6 MB

    prep_kernel<<<dim3(2112), 256, 0, stream>>>(x, qkvw, pw, xh, wqkvT, pwT);
    qkv_mfma_kernel<<<dim3(24, 32), 256, 0, stream>>>(xh, wqkvT, qkvb,
                                                      qbh, kbh, vbT);
    flash_mfma_kernel<<<dim3(64, NHEADS), 256, 0, stream>>>(qbh, kbh, vbT,
                                                            rpw, rph, aob);
    proj_mfma_kernel<<<dim3(6, 64), 256, 0, stream>>>(aob, pwT, pb, out);
}

// Round 16
// 220.780 us; speedup vs baseline: 1.4159x; 1.1897x over previous
//
#include <hip/hip_runtime.h>
#include <math.h>

// Problem constants: B=1, H=W=64 (N=4096), C=768, 12 heads x hd=64.
#define NHEADS 12
#define NTOK 4096
#define LOG2E 1.44269504f

typedef __attribute__((ext_vector_type(8))) short bf8v;    // 8 x bf16
typedef __attribute__((ext_vector_type(4))) float f4v;     // 16x16 C/D frag
typedef __attribute__((ext_vector_type(16))) float f16v;   // 32x32 C/D frag

__device__ __forceinline__ unsigned short f2bf(float f) {
  unsigned int u = __float_as_uint(f);
  u += 0x7fffu + ((u >> 16) & 1u);   // RNE
  return (unsigned short)(u >> 16);
}
__device__ __forceinline__ bf8v pack8(float4 a, float4 b) {
  bf8v v;
  v[0] = (short)f2bf(a.x); v[1] = (short)f2bf(a.y);
  v[2] = (short)f2bf(a.z); v[3] = (short)f2bf(a.w);
  v[4] = (short)f2bf(b.x); v[5] = (short)f2bf(b.y);
  v[6] = (short)f2bf(b.z); v[7] = (short)f2bf(b.w);
  return v;
}
// pack two f32 (round via +0x8000) into (hi|lo) bf16 pair
__device__ __forceinline__ unsigned pkbf(float hi, float lo) {
  return __builtin_amdgcn_perm(__float_as_uint(hi) + 0x8000u,
                               __float_as_uint(lo) + 0x8000u, 0x07060302u);
}
__device__ __forceinline__ void gload_lds16(const void* g, void* l) {
  __builtin_amdgcn_global_load_lds(
      (const __attribute__((address_space(1))) void*)g,
      (__attribute__((address_space(3))) void*)l, 16, 0, 0);
}

// ---------------------------------------------------------------------------
// prep: unified x->bf16 cvt + qkv_w / proj_w transpose-cvt (one launch).
// blocks [0,1536): cvt; [1536,1968): tcvt qkvw; [1968,2112): tcvt pw.
// ---------------------------------------------------------------------------
__device__ __forceinline__ void tcvt_body(
    const float* __restrict__ in, short* __restrict__ out, int R, int C,
    int bx, int by, int t, float (*Ts)[65])
{
    const int bc = bx * 64, br = by * 64;
    {
        const int r = t >> 2, c0 = (t & 3) * 16;
        const float* src = in + (size_t)(br + r) * C + bc + c0;
#pragma unroll
        for (int i = 0; i < 4; ++i) {
            float4 a = *(const float4*)(src + 4 * i);
            Ts[r][c0 + 4 * i + 0] = a.x;
            Ts[r][c0 + 4 * i + 1] = a.y;
            Ts[r][c0 + 4 * i + 2] = a.z;
            Ts[r][c0 + 4 * i + 3] = a.w;
        }
    }
    __syncthreads();
    const int c = t >> 2, r0 = (t & 3) * 16;
    short* dst = out + (size_t)(bc + c) * R + br + r0;
#pragma unroll
    for (int p = 0; p < 2; ++p) {
        bf8v v;
#pragma unroll
        for (int i = 0; i < 8; ++i) v[i] = (short)f2bf(Ts[r0 + p * 8 + i][c]);
        *(bf8v*)(dst + p * 8) = v;
    }
}

__global__ __launch_bounds__(256) void prep_kernel(
    const float* __restrict__ x, const float* __restrict__ qkvw,
    const float* __restrict__ pw, short* __restrict__ xh,
    short* __restrict__ wqkvT, short* __restrict__ pwT)
{
    __shared__ float Ts[64][65];
    const int bid = blockIdx.x, t = threadIdx.x;
    if (bid < 1536) {
        const size_t i = ((size_t)bid * 256 + t) * 8;
        float4 a = *(const float4*)(x + i);
        float4 b = *(const float4*)(x + i + 4);
        *(bf8v*)(xh + i) = pack8(a, b);
    } else if (bid < 1968) {
        const int idx = bid - 1536;
        tcvt_body(qkvw, wqkvT, 768, 2304, idx % 36, idx / 36, t, Ts);
    } else {
        const int idx = bid - 1968;
        tcvt_body(pw, pwT, 768, 768, idx % 12, idx / 12, t, Ts);
    }
}

// ---------------------------------------------------------------------------
// QKV GEMM (MFMA bf16): 128x96 tile, grid (24,32)=768 blocks.
// ---------------------------------------------------------------------------
__global__ __launch_bounds__(256) void qkv_mfma_kernel(
    const short* __restrict__ xh, const short* __restrict__ wT,
    const float* __restrict__ bias, short* __restrict__ qbh,
    short* __restrict__ kbh, short* __restrict__ vbT)
{
    __shared__ __align__(16) short As[128 * 32];
    __shared__ __align__(16) short Bs[96 * 32];
    const int t = threadIdx.x;
    const int w = t >> 6, lane = t & 63;
    const int l15 = lane & 15, l4 = lane >> 4;
    const int wr = w >> 1, wc = w & 1;
    const int row0 = blockIdx.y * 128, col0 = blockIdx.x * 96;
    const int ldr = lane >> 2;
    const int ldk = (lane & 3) * 8;

    f4v acc[4][3] = {};
    const short* aBase = xh + (size_t)(row0 + w * 32 + ldr) * 768 + ldk;
    const short* bBase0 = wT + (size_t)(col0 + w * 16 + ldr) * 768 + ldk;
    const short* bBase1 = wT + (size_t)(col0 + 64 + w * 16 + ldr) * 768 + ldk;

    for (int kk = 0; kk < 768; kk += 32) {
        __syncthreads();
#pragma unroll
        for (int c = 0; c < 2; ++c)
            gload_lds16(aBase + (size_t)c * 16 * 768 + kk,
                        &As[(w * 32 + c * 16) * 32]);
        gload_lds16(bBase0 + kk, &Bs[(w * 16) * 32]);
        if (w < 2)   // wave-uniform: waves 0,1 stage B chunks 4,5
            gload_lds16(bBase1 + kk, &Bs[(64 + w * 16) * 32]);
        __syncthreads();
        bf8v af[4], bg[3];
#pragma unroll
        for (int i = 0; i < 4; ++i)
            af[i] = *(const bf8v*)&As[(wr * 64 + 16 * i + l15) * 32 + l4 * 8];
#pragma unroll
        for (int j = 0; j < 3; ++j)
            bg[j] = *(const bf8v*)&Bs[(wc * 48 + 16 * j + l15) * 32 + l4 * 8];
#pragma unroll
        for (int i = 0; i < 4; ++i)
#pragma unroll
            for (int j = 0; j < 3; ++j)
                acc[i][j] = __builtin_amdgcn_mfma_f32_16x16x32_bf16(
                    af[i], bg[j], acc[i][j], 0, 0, 0);
    }

#pragma unroll
    for (int j = 0; j < 3; ++j) {
        const int n = col0 + wc * 48 + 16 * j + l15;
        const int s = n / 768;            // block-uniform (96 | 768)
        const int rm = n - s * 768;
        const int h = rm >> 6, d = rm & 63;
        const float bv = bias[n];
        if (s == 2) {
            short* vdst = vbT + (size_t)(h * 64 + d) * NTOK;
#pragma unroll
            for (int i = 0; i < 4; ++i) {
                const int m = row0 + wr * 64 + 16 * i + l4 * 4;
                short4 pv;
                pv.x = (short)f2bf(acc[i][j][0] + bv);
                pv.y = (short)f2bf(acc[i][j][1] + bv);
                pv.z = (short)f2bf(acc[i][j][2] + bv);
                pv.w = (short)f2bf(acc[i][j][3] + bv);
                *(short4*)(vdst + m) = pv;
            }
        } else {
            short* dst = (s == 0) ? qbh : kbh;
#pragma unroll
            for (int i = 0; i < 4; ++i) {
                const int m = row0 + wr * 64 + 16 * i + l4 * 4;
#pragma unroll
                for (int r = 0; r < 4; ++r)
                    dst[((size_t)h * NTOK + m + r) * 64 + d] =
                        (short)f2bf(acc[i][j][r] + bv);
            }
        }
    }
}

// ---------------------------------------------------------------------------
// Flash attention (R12 proven form): 32x32x16 MFMA, fused rel-pos prologue,
// LDS-staged K AND V (both removal attempts regressed: R14 occupancy
// collapse at 128-thr blocks, R15 vB spill + gather latency).
// __shared__ union keeps true addrspace(3) (R11 flat-op lesson).
// ---------------------------------------------------------------------------
union FlashSMem {
    struct {
        short Ks[128][68];     // 17408 B  [tok][d], pad 4
        short Vt[64][132];     // 16896 B  [d][tok], pad 4
        float relHs[64][65];   // 16640 B  [kh][q-local] (log2e)
    };
    float U[128 * 65];         // 33280 B  prologue overlay (within Ks+Vt)
    struct {
        float OEp[64][64];     // 16384 B  epilogue O-combine
        float lEp[64];         //   256 B  epilogue l-combine
    };
};

__global__ __launch_bounds__(256, 3) void flash_mfma_kernel(
    const short* __restrict__ qbh, const short* __restrict__ kbh,
    const short* __restrict__ vbT, const float* __restrict__ rpw,
    const float* __restrict__ rph, short* __restrict__ aob)
{
    __shared__ __align__(16) FlashSMem sm;

    const int t = threadIdx.x;
    const int qt = blockIdx.x, head = blockIdx.y;
    const int row0 = qt * 64;
    const int lane = t & 63, w = t >> 6;
    const int qh2 = w & 1, th = w >> 1;
    const int l31 = lane & 31, hf = lane >> 5;
    const size_t hB = (size_t)head * NTOK * 64;
    const float SC = 0.125f * LOG2E;

    // Q as 32x32 B-fragments: B[k=d][n=q], lane n=l31, k = 8*hf + j
    const int q = row0 + qh2 * 32 + l31;
    bf8v bQ[4];
    {
        const short* qsrc = qbh + hB + (size_t)q * 64;
#pragma unroll
        for (int ks = 0; ks < 4; ++ks)
            bQ[ks] = *(const bf8v*)(qsrc + ks * 16 + hf * 8);
    }
    // prefetch K/V tile 0 into registers
    const int sx = t >> 2;            // K token row (and V d-row)
    const int sck = (t & 3) * 16;     // K d-offset (shorts)
    const int scv = (t & 3) * 32;     // V token-offset (shorts)
    const short* kptr = kbh + hB + (size_t)sx * 64 + sck;
    const short* vptr = vbT + ((size_t)head * 64 + sx) * NTOK + scv;
    bf8v kpf[4], vpf[4];
    kpf[0] = *(const bf8v*)(kptr);
    kpf[1] = *(const bf8v*)(kptr + 8);
    kpf[2] = *(const bf8v*)(kptr + 64 * 64);
    kpf[3] = *(const bf8v*)(kptr + 64 * 64 + 8);
    vpf[0] = *(const bf8v*)(vptr);
    vpf[1] = *(const bf8v*)(vptr + 8);
    vpf[2] = *(const bf8v*)(vptr + 16);
    vpf[3] = *(const bf8v*)(vptr + 24);

    // --- fused relW: U[j][qw] = sum_d rpw[j][d] Q[qw][d]; row j=127 never
    // gathered (qw+63-kw <= 126) -> clamp its load to row 0.
#pragma unroll
    for (int jt2 = 0; jt2 < 2; ++jt2) {
        const int jt = 2 * th + jt2;
        int j = jt * 32 + l31;
        if (j > 126) j = 0;
        const float* asrc = rpw + (size_t)j * 64;
        f16v c = {};
#pragma unroll
        for (int ks = 0; ks < 4; ++ks) {
            float4 u0 = *(const float4*)(asrc + ks * 16 + hf * 8);
            float4 u1 = *(const float4*)(asrc + ks * 16 + hf * 8 + 4);
            c = __builtin_amdgcn_mfma_f32_32x32x16_bf16(
                pack8(u0, u1), bQ[ks], c, 0, 0, 0);
        }
#pragma unroll
        for (int reg = 0; reg < 16; ++reg)
            sm.U[(jt * 32 + (reg & 3) + 8 * (reg >> 2) + 4 * hf) * 65 +
                 qh2 * 32 + l31] = c[reg];
    }
    __syncthreads();
    // gather relW into packed-bf16 registers (LOG2E-scaled)
    const int qw = qh2 * 32 + l31;
    uint2 rwp[2][4];
#pragma unroll
    for (int t32 = 0; t32 < 2; ++t32)
#pragma unroll
        for (int g = 0; g < 4; ++g) {
            const int kw = t32 * 32 + 8 * g + 4 * hf;
            const float v0 = sm.U[(qw + 63 - kw) * 65 + qw] * LOG2E;
            const float v1 = sm.U[(qw + 62 - kw) * 65 + qw] * LOG2E;
            const float v2 = sm.U[(qw + 61 - kw) * 65 + qw] * LOG2E;
            const float v3 = sm.U[(qw + 60 - kw) * 65 + qw] * LOG2E;
            rwp[t32][g].x = pkbf(v1, v0);
            rwp[t32][g].y = pkbf(v3, v2);
        }
    __syncthreads();   // U reads done before relHs (and Ks/Vt) overwrites

    // --- fused relH: relHs[kh][q] = LOG2E * (rph[qt+63-kh] . Q[q])
    {
        const int kh = th * 32 + l31;
        const float* asrc = rph + (size_t)(qt + 63 - kh) * 64;
        f16v c = {};
#pragma unroll
        for (int ks = 0; ks < 4; ++ks) {
            float4 u0 = *(const float4*)(asrc + ks * 16 + hf * 8);
            float4 u1 = *(const float4*)(asrc + ks * 16 + hf * 8 + 4);
            u0.x *= LOG2E; u0.y *= LOG2E; u0.z *= LOG2E; u0.w *= LOG2E;
            u1.x *= LOG2E; u1.y *= LOG2E; u1.z *= LOG2E; u1.w *= LOG2E;
            c = __builtin_amdgcn_mfma_f32_32x32x16_bf16(
                pack8(u0, u1), bQ[ks], c, 0, 0, 0);
        }
#pragma unroll
        for (int reg = 0; reg < 16; ++reg)
            sm.relHs[th * 32 + (reg & 3) + 8 * (reg >> 2) + 4 * hf]
                    [qh2 * 32 + l31] = c[reg];
    }
    // (loop-top barrier makes relHs visible before first read)

    f16v O[2] = {{}, {}};   // ntile: d = ntile*32+l31; rows q (C layout)
    float lsum = 0.f;

    for (int it = 0; it < 32; ++it) {
        __syncthreads();
        *(bf8v*)&sm.Ks[sx][sck] = kpf[0];
        *(bf8v*)&sm.Ks[sx][sck + 8] = kpf[1];
        *(bf8v*)&sm.Ks[sx + 64][sck] = kpf[2];
        *(bf8v*)&sm.Ks[sx + 64][sck + 8] = kpf[3];
        *(bf8v*)&sm.Vt[sx][scv] = vpf[0];
        *(bf8v*)&sm.Vt[sx][scv + 8] = vpf[1];
        *(bf8v*)&sm.Vt[sx][scv + 16] = vpf[2];
        *(bf8v*)&sm.Vt[sx][scv + 24] = vpf[3];
        {
            const int itn = (it < 31) ? it + 1 : 31;
            const short* kp = kptr + (size_t)itn * 128 * 64;
            const short* vp = vptr + itn * 128;
            kpf[0] = *(const bf8v*)kp;
            kpf[1] = *(const bf8v*)(kp + 8);
            kpf[2] = *(const bf8v*)(kp + 64 * 64);
            kpf[3] = *(const bf8v*)(kp + 64 * 64 + 8);
            vpf[0] = *(const bf8v*)vp;
            vpf[1] = *(const bf8v*)(vp + 8);
            vpf[2] = *(const bf8v*)(vp + 16);
            vpf[3] = *(const bf8v*)(vp + 24);
        }
        __syncthreads();

        // S^T: A = K tokens (this wave's half), B = bQ
        f16v acc[2] = {{}, {}};
#pragma unroll
        for (int ks = 0; ks < 4; ++ks)
#pragma unroll
            for (int t32 = 0; t32 < 2; ++t32)
                acc[t32] = __builtin_amdgcn_mfma_f32_32x32x16_bf16(
                    *(const bf8v*)&sm.Ks[th * 64 + t32 * 32 + l31]
                                        [ks * 16 + hf * 8],
                    bQ[ks], acc[t32], 0, 0, 0);

        const float rh = sm.relHs[2 * it + th][qh2 * 32 + l31];

        // e = exp2(SC*acc + rw + rh); pack to bf16 pairs per 4-row group
        unsigned xg[2][4], yg[2][4];
#pragma unroll
        for (int t32 = 0; t32 < 2; ++t32) {
            float sub = 0.f;
#pragma unroll
            for (int g = 0; g < 4; ++g) {
                const unsigned u0 = rwp[t32][g].x;
                const unsigned u1 = rwp[t32][g].y;
                const float b0 = __uint_as_float(u0 << 16) + rh;
                const float b1 = __uint_as_float(u0 & 0xffff0000u) + rh;
                const float b2 = __uint_as_float(u1 << 16) + rh;
                const float b3 = __uint_as_float(u1 & 0xffff0000u) + rh;
                const float e0 = __builtin_amdgcn_exp2f(
                    fmaf(acc[t32][4 * g + 0], SC, b0));
                const float e1 = __builtin_amdgcn_exp2f(
                    fmaf(acc[t32][4 * g + 1], SC, b1));
                const float e2 = __builtin_amdgcn_exp2f(
                    fmaf(acc[t32][4 * g + 2], SC, b2));
                const float e3 = __builtin_amdgcn_exp2f(
                    fmaf(acc[t32][4 * g + 3], SC, b3));
                sub += (e0 + e1) + (e2 + e3);
                xg[t32][g] = pkbf(e1, e0);
                yg[t32][g] = pkbf(e3, e2);
            }
            lsum += sub;
        }

        // PV: A-frag via permlane32_swap pairs; B from Vt
#pragma unroll
        for (int t32 = 0; t32 < 2; ++t32)
#pragma unroll
            for (int ks2 = 0; ks2 < 2; ++ks2) {
                auto px = __builtin_amdgcn_permlane32_swap(
                    xg[t32][2 * ks2], xg[t32][2 * ks2 + 1], false, false);
                auto py = __builtin_amdgcn_permlane32_swap(
                    yg[t32][2 * ks2], yg[t32][2 * ks2 + 1], false, false);
                int4 av;
                av.x = (int)px[0];
                av.y = (int)py[0];
                av.z = (int)px[1];
                av.w = (int)py[1];
                union { int4 i; bf8v v; } u; u.i = av;
#pragma unroll
                for (int nt = 0; nt < 2; ++nt)
                    O[nt] = __builtin_amdgcn_mfma_f32_32x32x16_bf16(
                        u.v,
                        *(const bf8v*)&sm.Vt[nt * 32 + l31]
                                            [th * 64 + t32 * 32 + ks2 * 16 +
                                             hf * 8],
                        O[nt], 0, 0, 0);
            }
    }

    // epilogue: lanes l / l+32 share q -> reduce; then combine the two
    // token-half waves (th) via LDS union members, normalize, store.
    lsum += __shfl_xor(lsum, 32);
    __syncthreads();
    if (th == 1) {
#pragma unroll
        for (int nt = 0; nt < 2; ++nt)
#pragma unroll
            for (int reg = 0; reg < 16; ++reg) {
                const int qr = (reg & 3) + 8 * (reg >> 2) + 4 * hf;
                sm.OEp[qh2 * 32 + qr][nt * 32 + l31] = O[nt][reg];
            }
        if (lane < 32) sm.lEp[qh2 * 32 + l31] = lsum;
    }
    __syncthreads();
    if (th == 0) {
        lsum += sm.lEp[qh2 * 32 + l31];
        const float linv = 1.0f / lsum;
#pragma unroll
        for (int nt = 0; nt < 2; ++nt)
#pragma unroll
            for (int reg = 0; reg < 16; ++reg) {
                const int qr = (reg & 3) + 8 * (reg >> 2) + 4 * hf;
                const float li = __shfl(linv, qr);
                const float o =
                    O[nt][reg] + sm.OEp[qh2 * 32 + qr][nt * 32 + l31];
                aob[(size_t)(row0 + qh2 * 32 + qr) * 768 + head * 64 +
                    nt * 32 + l31] = (short)f2bf(o * li);
            }
    }
}

// ---------------------------------------------------------------------------
// proj GEMM (MFMA bf16), 64x128 tile -> 384 blocks.
// ---------------------------------------------------------------------------
__global__ __launch_bounds__(256) void proj_mfma_kernel(
    const short* __restrict__ aoh, const short* __restrict__ pwT,
    const float* __restrict__ bias, float* __restrict__ out)
{
    __shared__ __align__(16) short As[64 * 32];
    __shared__ __align__(16) short Bs[128 * 32];
    const int t = threadIdx.x;
    const int w = t >> 6, lane = t & 63;
    const int l15 = lane & 15, l4 = lane >> 4;
    const int wr = w >> 1, wc = w & 1;
    const int row0 = blockIdx.y * 64, col0 = blockIdx.x * 128;
    const int ldr = lane >> 2;
    const int ldk = (lane & 3) * 8;

    f4v acc[2][4] = {};
    const short* aBase = aoh + (size_t)(row0 + w * 16 + ldr) * 768 + ldk;
    const short* bBase = pwT + (size_t)(col0 + w * 32 + ldr) * 768 + ldk;

    for (int kk = 0; kk < 768; kk += 32) {
        __syncthreads();
        gload_lds16(aBase + kk, &As[(w * 16) * 32]);
#pragma unroll
        for (int c = 0; c < 2; ++c)
            gload_lds16(bBase + (size_t)c * 16 * 768 + kk,
                        &Bs[(w * 32 + c * 16) * 32]);
        __syncthreads();
        bf8v af[2], bg[4];
#pragma unroll
        for (int i = 0; i < 2; ++i)
            af[i] = *(const bf8v*)&As[(wr * 32 + 16 * i + l15) * 32 + l4 * 8];
#pragma unroll
        for (int j = 0; j < 4; ++j)
            bg[j] = *(const bf8v*)&Bs[(wc * 64 + 16 * j + l15) * 32 + l4 * 8];
#pragma unroll
        for (int i = 0; i < 2; ++i)
#pragma unroll
            for (int j = 0; j < 4; ++j)
                acc[i][j] = __builtin_amdgcn_mfma_f32_16x16x32_bf16(
                    af[i], bg[j], acc[i][j], 0, 0, 0);
    }

#pragma unroll
    for (int j = 0; j < 4; ++j) {
        const int n = col0 + wc * 64 + 16 * j + l15;
        const float bv = bias[n];
#pragma unroll
        for (int i = 0; i < 2; ++i) {
            const int m = row0 + wr * 32 + 16 * i + l4 * 4;
#pragma unroll
            for (int r = 0; r < 4; ++r)
                out[(size_t)(m + r) * 768 + n] = acc[i][j][r] + bv;
        }
    }
}

// ---------------------------------------------------------------------------
extern "C" void kernel_launch(void* const* d_in, const int* in_sizes, int n_in,
                              void* d_out, int out_size, void* d_ws,
                              size_t ws_size, hipStream_t stream)
{
    (void)in_sizes; (void)n_in; (void)out_size; (void)ws_size;
    const float* x    = (const float*)d_in[0];
    const float* qkvw = (const float*)d_in[1];
    const float* qkvb = (const float*)d_in[2];
    const float* pw   = (const float*)d_in[3];
    const float* pb   = (const float*)d_in[4];
    const float* rph  = (const float*)d_in[5];
    const float* rpw  = (const float*)d_in[6];
    float* out = (float*)d_out;

    const size_t S = (size_t)NHEADS * NTOK * 64;  // 3,145,728 (= 4096*768)
    short* qbh  = (short*)d_ws;          // S bf16   q  [h][tok][d]
    short* kbh  = qbh + S;               // S bf16   k  [h][tok][d]
    short* vbT  = kbh + S;               // S bf16   v^T [h][d][tok]
    short* xh   = vbT + S;               // S bf16   x [tok][c]; dead after
    short* aob  = xh;                    //   qkv -> aliased as attn out
    short* wqkvT = xh + S;               // 2304*768 bf16
    short* pwT  = wqkvT + (size_t)2304 * 768;  // 768*768 bf16
    // total ~29.6 MB

    prep_kernel<<<dim3(2112), 256, 0, stream>>>(x, qkvw, pw, xh, wqkvT, pwT);
    qkv_mfma_kernel<<<dim3(24, 32), 256, 0, stream>>>(xh, wqkvT, qkvb,
                                                      qbh, kbh, vbT);
    flash_mfma_kernel<<<dim3(64, NHEADS), 256, 0, stream>>>(qbh, kbh, vbT,
                                                            rpw, rph, aob);
    proj_mfma_kernel<<<dim3(6, 64), 256, 0, stream>>>(aob, pwT, pb, out);
}

// Round 17
// 211.365 us; speedup vs baseline: 1.4789x; 1.0445x over previous
//
#include <hip/hip_runtime.h>
#include <math.h>

// Problem constants: B=1, H=W=64 (N=4096), C=768, 12 heads x hd=64.
#define NHEADS 12
#define NTOK 4096
#define LOG2E 1.44269504f

typedef __attribute__((ext_vector_type(8))) short bf8v;    // 8 x bf16
typedef __attribute__((ext_vector_type(4))) float f4v;     // 16x16 C/D frag
typedef __attribute__((ext_vector_type(16))) float f16v;   // 32x32 C/D frag

__device__ __forceinline__ unsigned short f2bf(float f) {
  unsigned int u = __float_as_uint(f);
  u += 0x7fffu + ((u >> 16) & 1u);   // RNE
  return (unsigned short)(u >> 16);
}
__device__ __forceinline__ bf8v pack8(float4 a, float4 b) {
  bf8v v;
  v[0] = (short)f2bf(a.x); v[1] = (short)f2bf(a.y);
  v[2] = (short)f2bf(a.z); v[3] = (short)f2bf(a.w);
  v[4] = (short)f2bf(b.x); v[5] = (short)f2bf(b.y);
  v[6] = (short)f2bf(b.z); v[7] = (short)f2bf(b.w);
  return v;
}
// pack two f32 (round via +0x8000) into (hi|lo) bf16 pair
__device__ __forceinline__ unsigned pkbf(float hi, float lo) {
  return __builtin_amdgcn_perm(__float_as_uint(hi) + 0x8000u,
                               __float_as_uint(lo) + 0x8000u, 0x07060302u);
}
__device__ __forceinline__ void gload_lds16(const void* g, void* l) {
  __builtin_amdgcn_global_load_lds(
      (const __attribute__((address_space(1))) void*)g,
      (__attribute__((address_space(3))) void*)l, 16, 0, 0);
}

// ---------------------------------------------------------------------------
// prep: unified x->bf16 cvt + qkv_w / proj_w transpose-cvt (one launch).
// blocks [0,1536): cvt; [1536,1968): tcvt qkvw; [1968,2112): tcvt pw.
// ---------------------------------------------------------------------------
__device__ __forceinline__ void tcvt_body(
    const float* __restrict__ in, short* __restrict__ out, int R, int C,
    int bx, int by, int t, float (*Ts)[65])
{
    const int bc = bx * 64, br = by * 64;
    {
        const int r = t >> 2, c0 = (t & 3) * 16;
        const float* src = in + (size_t)(br + r) * C + bc + c0;
#pragma unroll
        for (int i = 0; i < 4; ++i) {
            float4 a = *(const float4*)(src + 4 * i);
            Ts[r][c0 + 4 * i + 0] = a.x;
            Ts[r][c0 + 4 * i + 1] = a.y;
            Ts[r][c0 + 4 * i + 2] = a.z;
            Ts[r][c0 + 4 * i + 3] = a.w;
        }
    }
    __syncthreads();
    const int c = t >> 2, r0 = (t & 3) * 16;
    short* dst = out + (size_t)(bc + c) * R + br + r0;
#pragma unroll
    for (int p = 0; p < 2; ++p) {
        bf8v v;
#pragma unroll
        for (int i = 0; i < 8; ++i) v[i] = (short)f2bf(Ts[r0 + p * 8 + i][c]);
        *(bf8v*)(dst + p * 8) = v;
    }
}

__global__ __launch_bounds__(256) void prep_kernel(
    const float* __restrict__ x, const float* __restrict__ qkvw,
    const float* __restrict__ pw, short* __restrict__ xh,
    short* __restrict__ wqkvT, short* __restrict__ pwT)
{
    __shared__ float Ts[64][65];
    const int bid = blockIdx.x, t = threadIdx.x;
    if (bid < 1536) {
        const size_t i = ((size_t)bid * 256 + t) * 8;
        float4 a = *(const float4*)(x + i);
        float4 b = *(const float4*)(x + i + 4);
        *(bf8v*)(xh + i) = pack8(a, b);
    } else if (bid < 1968) {
        const int idx = bid - 1536;
        tcvt_body(qkvw, wqkvT, 768, 2304, idx % 36, idx / 36, t, Ts);
    } else {
        const int idx = bid - 1968;
        tcvt_body(pw, pwT, 768, 768, idx % 12, idx / 12, t, Ts);
    }
}

// ---------------------------------------------------------------------------
// QKV GEMM (MFMA bf16): 128x96 tile, grid (24,32)=768 blocks.
// V epilogue now writes the BLOCKED layout vblk[h][tok/16][d][tok%16]
// (same short4 store pattern; only address math changed) so flash can read
// V fragments straight from global fully coalesced.
// ---------------------------------------------------------------------------
__global__ __launch_bounds__(256) void qkv_mfma_kernel(
    const short* __restrict__ xh, const short* __restrict__ wT,
    const float* __restrict__ bias, short* __restrict__ qbh,
    short* __restrict__ kbh, short* __restrict__ vblk)
{
    __shared__ __align__(16) short As[128 * 32];
    __shared__ __align__(16) short Bs[96 * 32];
    const int t = threadIdx.x;
    const int w = t >> 6, lane = t & 63;
    const int l15 = lane & 15, l4 = lane >> 4;
    const int wr = w >> 1, wc = w & 1;
    const int row0 = blockIdx.y * 128, col0 = blockIdx.x * 96;
    const int ldr = lane >> 2;
    const int ldk = (lane & 3) * 8;

    f4v acc[4][3] = {};
    const short* aBase = xh + (size_t)(row0 + w * 32 + ldr) * 768 + ldk;
    const short* bBase0 = wT + (size_t)(col0 + w * 16 + ldr) * 768 + ldk;
    const short* bBase1 = wT + (size_t)(col0 + 64 + w * 16 + ldr) * 768 + ldk;

    for (int kk = 0; kk < 768; kk += 32) {
        __syncthreads();
#pragma unroll
        for (int c = 0; c < 2; ++c)
            gload_lds16(aBase + (size_t)c * 16 * 768 + kk,
                        &As[(w * 32 + c * 16) * 32]);
        gload_lds16(bBase0 + kk, &Bs[(w * 16) * 32]);
        if (w < 2)   // wave-uniform: waves 0,1 stage B chunks 4,5
            gload_lds16(bBase1 + kk, &Bs[(64 + w * 16) * 32]);
        __syncthreads();
        bf8v af[4], bg[3];
#pragma unroll
        for (int i = 0; i < 4; ++i)
            af[i] = *(const bf8v*)&As[(wr * 64 + 16 * i + l15) * 32 + l4 * 8];
#pragma unroll
        for (int j = 0; j < 3; ++j)
            bg[j] = *(const bf8v*)&Bs[(wc * 48 + 16 * j + l15) * 32 + l4 * 8];
#pragma unroll
        for (int i = 0; i < 4; ++i)
#pragma unroll
            for (int j = 0; j < 3; ++j)
                acc[i][j] = __builtin_amdgcn_mfma_f32_16x16x32_bf16(
                    af[i], bg[j], acc[i][j], 0, 0, 0);
    }

#pragma unroll
    for (int j = 0; j < 3; ++j) {
        const int n = col0 + wc * 48 + 16 * j + l15;
        const int s = n / 768;            // block-uniform (96 | 768)
        const int rm = n - s * 768;
        const int h = rm >> 6, d = rm & 63;
        const float bv = bias[n];
        if (s == 2) {
#pragma unroll
            for (int i = 0; i < 4; ++i) {
                const int m = row0 + wr * 64 + 16 * i + l4 * 4;
                short4 pv;
                pv.x = (short)f2bf(acc[i][j][0] + bv);
                pv.y = (short)f2bf(acc[i][j][1] + bv);
                pv.z = (short)f2bf(acc[i][j][2] + bv);
                pv.w = (short)f2bf(acc[i][j][3] + bv);
                // blocked: [h][m>>4][d][m&15]; m&15 = l4*4 (short4-aligned)
                *(short4*)(vblk +
                           ((size_t)(h * 256 + (m >> 4)) * 64 + d) * 16 +
                           (m & 15)) = pv;
            }
        } else {
            short* dst = (s == 0) ? qbh : kbh;
#pragma unroll
            for (int i = 0; i < 4; ++i) {
                const int m = row0 + wr * 64 + 16 * i + l4 * 4;
#pragma unroll
                for (int r = 0; r < 4; ++r)
                    dst[((size_t)h * NTOK + m + r) * 64 + d] =
                        (short)f2bf(acc[i][j][r] + bv);
            }
        }
    }
}

// ---------------------------------------------------------------------------
// Flash attention v10: R16 structure, Vt tile DELETED. V B-frags load
// directly from the blocked global layout (fully coalesced 32B/lane runs),
// placed AFTER the staging barrier and right before PV (short liveness — the
// R15 spill came from vB held across both barriers). LDS 51.2 -> 34 KB.
// WRITE_SIZE is the spill sentinel.
// ---------------------------------------------------------------------------
union FlashSMem {
    struct {
        short Ks[128][68];     // 17408 B  [tok][d], pad 4
        float relHs[64][65];   // 16640 B  [kh][q-local] (log2e)
    };
    float U[128 * 65];         // 33280 B  prologue overlay
    struct {
        float OEp[64][64];     // 16384 B  epilogue O-combine
        float lEp[64];         //   256 B  epilogue l-combine
    };
};

__global__ __launch_bounds__(256, 3) void flash_mfma_kernel(
    const short* __restrict__ qbh, const short* __restrict__ kbh,
    const short* __restrict__ vblk, const float* __restrict__ rpw,
    const float* __restrict__ rph, short* __restrict__ aob)
{
    __shared__ __align__(16) FlashSMem sm;

    const int t = threadIdx.x;
    const int qt = blockIdx.x, head = blockIdx.y;
    const int row0 = qt * 64;
    const int lane = t & 63, w = t >> 6;
    const int qh2 = w & 1, th = w >> 1;
    const int l31 = lane & 31, hf = lane >> 5;
    const size_t hB = (size_t)head * NTOK * 64;
    const float SC = 0.125f * LOG2E;

    // Q as 32x32 B-fragments: B[k=d][n=q], lane n=l31, k = 8*hf + j
    const int q = row0 + qh2 * 32 + l31;
    bf8v bQ[4];
    {
        const short* qsrc = qbh + hB + (size_t)q * 64;
#pragma unroll
        for (int ks = 0; ks < 4; ++ks)
            bQ[ks] = *(const bf8v*)(qsrc + ks * 16 + hf * 8);
    }
    // K staging pointers + blocked-V fragment base
    const int sx = t >> 2;            // K token row
    const int sck = (t & 3) * 16;     // K d-offset (shorts)
    const short* kptr = kbh + hB + (size_t)sx * 64 + sck;
    // V frag (it,th,t32,ks2,nt): blk = it*8+th*4+t32*2+ks2;
    // addr = vblk + ((head*256+blk)*64 + nt*32 + l31)*16 + hf*8
    const short* vb2 = vblk + ((size_t)head * 256 * 64 + l31) * 16 + hf * 8;
    bf8v kpf[4];
    kpf[0] = *(const bf8v*)(kptr);
    kpf[1] = *(const bf8v*)(kptr + 8);
    kpf[2] = *(const bf8v*)(kptr + 64 * 64);
    kpf[3] = *(const bf8v*)(kptr + 64 * 64 + 8);

    // --- fused relW: U[j][qw] = sum_d rpw[j][d] Q[qw][d]; row j=127 never
    // gathered (qw+63-kw <= 126) -> clamp its load to row 0.
#pragma unroll
    for (int jt2 = 0; jt2 < 2; ++jt2) {
        const int jt = 2 * th + jt2;
        int j = jt * 32 + l31;
        if (j > 126) j = 0;
        const float* asrc = rpw + (size_t)j * 64;
        f16v c = {};
#pragma unroll
        for (int ks = 0; ks < 4; ++ks) {
            float4 u0 = *(const float4*)(asrc + ks * 16 + hf * 8);
            float4 u1 = *(const float4*)(asrc + ks * 16 + hf * 8 + 4);
            c = __builtin_amdgcn_mfma_f32_32x32x16_bf16(
                pack8(u0, u1), bQ[ks], c, 0, 0, 0);
        }
#pragma unroll
        for (int reg = 0; reg < 16; ++reg)
            sm.U[(jt * 32 + (reg & 3) + 8 * (reg >> 2) + 4 * hf) * 65 +
                 qh2 * 32 + l31] = c[reg];
    }
    __syncthreads();
    // gather relW into packed-bf16 registers (LOG2E-scaled)
    const int qw = qh2 * 32 + l31;
    uint2 rwp[2][4];
#pragma unroll
    for (int t32 = 0; t32 < 2; ++t32)
#pragma unroll
        for (int g = 0; g < 4; ++g) {
            const int kw = t32 * 32 + 8 * g + 4 * hf;
            const float v0 = sm.U[(qw + 63 - kw) * 65 + qw] * LOG2E;
            const float v1 = sm.U[(qw + 62 - kw) * 65 + qw] * LOG2E;
            const float v2 = sm.U[(qw + 61 - kw) * 65 + qw] * LOG2E;
            const float v3 = sm.U[(qw + 60 - kw) * 65 + qw] * LOG2E;
            rwp[t32][g].x = pkbf(v1, v0);
            rwp[t32][g].y = pkbf(v3, v2);
        }
    __syncthreads();   // U reads done before relHs (and Ks) overwrites

    // --- fused relH: relHs[kh][q] = LOG2E * (rph[qt+63-kh] . Q[q])
    {
        const int kh = th * 32 + l31;
        const float* asrc = rph + (size_t)(qt + 63 - kh) * 64;
        f16v c = {};
#pragma unroll
        for (int ks = 0; ks < 4; ++ks) {
            float4 u0 = *(const float4*)(asrc + ks * 16 + hf * 8);
            float4 u1 = *(const float4*)(asrc + ks * 16 + hf * 8 + 4);
            u0.x *= LOG2E; u0.y *= LOG2E; u0.z *= LOG2E; u0.w *= LOG2E;
            u1.x *= LOG2E; u1.y *= LOG2E; u1.z *= LOG2E; u1.w *= LOG2E;
            c = __builtin_amdgcn_mfma_f32_32x32x16_bf16(
                pack8(u0, u1), bQ[ks], c, 0, 0, 0);
        }
#pragma unroll
        for (int reg = 0; reg < 16; ++reg)
            sm.relHs[th * 32 + (reg & 3) + 8 * (reg >> 2) + 4 * hf]
                    [qh2 * 32 + l31] = c[reg];
    }
    // (loop-top barrier makes relHs visible before first read)

    f16v O[2] = {{}, {}};   // ntile: d = ntile*32+l31; rows q (C layout)
    float lsum = 0.f;

    for (int it = 0; it < 32; ++it) {
        __syncthreads();
        *(bf8v*)&sm.Ks[sx][sck] = kpf[0];
        *(bf8v*)&sm.Ks[sx][sck + 8] = kpf[1];
        *(bf8v*)&sm.Ks[sx + 64][sck] = kpf[2];
        *(bf8v*)&sm.Ks[sx + 64][sck + 8] = kpf[3];
        {
            const int itn = (it < 31) ? it + 1 : 31;
            const short* kp = kptr + (size_t)itn * 128 * 64;
            kpf[0] = *(const bf8v*)kp;
            kpf[1] = *(const bf8v*)(kp + 8);
            kpf[2] = *(const bf8v*)(kp + 64 * 64);
            kpf[3] = *(const bf8v*)(kp + 64 * 64 + 8);
        }
        __syncthreads();

        // S^T: A = K tokens (this wave's half), B = bQ
        f16v acc[2] = {{}, {}};
#pragma unroll
        for (int ks = 0; ks < 4; ++ks)
#pragma unroll
            for (int t32 = 0; t32 < 2; ++t32)
                acc[t32] = __builtin_amdgcn_mfma_f32_32x32x16_bf16(
                    *(const bf8v*)&sm.Ks[th * 64 + t32 * 32 + l31]
                                        [ks * 16 + hf * 8],
                    bQ[ks], acc[t32], 0, 0, 0);

        // V frags: issue now (after S MFMAs, ~40 VALU of softmax cover the
        // L2 latency; liveness does NOT cross a barrier — R15 spill lesson)
        bf8v vB[2][2][2];   // [t32][ks2][nt]
        {
            const short* vit = vb2 + (size_t)(it * 8 + th * 4) * 64 * 16;
#pragma unroll
            for (int t32 = 0; t32 < 2; ++t32)
#pragma unroll
                for (int ks2 = 0; ks2 < 2; ++ks2)
#pragma unroll
                    for (int nt = 0; nt < 2; ++nt)
                        vB[t32][ks2][nt] = *(const bf8v*)(
                            vit + ((size_t)(t32 * 2 + ks2) * 64 + nt * 32) *
                                      16);
        }

        const float rh = sm.relHs[2 * it + th][qh2 * 32 + l31];

        // e = exp2(SC*acc + rw + rh); pack to bf16 pairs per 4-row group
        unsigned xg[2][4], yg[2][4];
#pragma unroll
        for (int t32 = 0; t32 < 2; ++t32) {
            float sub = 0.f;
#pragma unroll
            for (int g = 0; g < 4; ++g) {
                const unsigned u0 = rwp[t32][g].x;
                const unsigned u1 = rwp[t32][g].y;
                const float b0 = __uint_as_float(u0 << 16) + rh;
                const float b1 = __uint_as_float(u0 & 0xffff0000u) + rh;
                const float b2 = __uint_as_float(u1 << 16) + rh;
                const float b3 = __uint_as_float(u1 & 0xffff0000u) + rh;
                const float e0 = __builtin_amdgcn_exp2f(
                    fmaf(acc[t32][4 * g + 0], SC, b0));
                const float e1 = __builtin_amdgcn_exp2f(
                    fmaf(acc[t32][4 * g + 1], SC, b1));
                const float e2 = __builtin_amdgcn_exp2f(
                    fmaf(acc[t32][4 * g + 2], SC, b2));
                const float e3 = __builtin_amdgcn_exp2f(
                    fmaf(acc[t32][4 * g + 3], SC, b3));
                sub += (e0 + e1) + (e2 + e3);
                xg[t32][g] = pkbf(e1, e0);
                yg[t32][g] = pkbf(e3, e2);
            }
            lsum += sub;
        }

        // PV: A-frag via permlane32_swap pairs; B = direct-loaded V frags
#pragma unroll
        for (int t32 = 0; t32 < 2; ++t32)
#pragma unroll
            for (int ks2 = 0; ks2 < 2; ++ks2) {
                auto px = __builtin_amdgcn_permlane32_swap(
                    xg[t32][2 * ks2], xg[t32][2 * ks2 + 1], false, false);
                auto py = __builtin_amdgcn_permlane32_swap(
                    yg[t32][2 * ks2], yg[t32][2 * ks2 + 1], false, false);
                int4 av;
                av.x = (int)px[0];
                av.y = (int)py[0];
                av.z = (int)px[1];
                av.w = (int)py[1];
                union { int4 i; bf8v v; } u; u.i = av;
#pragma unroll
                for (int nt = 0; nt < 2; ++nt)
                    O[nt] = __builtin_amdgcn_mfma_f32_32x32x16_bf16(
                        u.v, vB[t32][ks2][nt], O[nt], 0, 0, 0);
            }
    }

    // epilogue: lanes l / l+32 share q -> reduce; then combine the two
    // token-half waves (th) via LDS union members, normalize, store.
    lsum += __shfl_xor(lsum, 32);
    __syncthreads();
    if (th == 1) {
#pragma unroll
        for (int nt = 0; nt < 2; ++nt)
#pragma unroll
            for (int reg = 0; reg < 16; ++reg) {
                const int qr = (reg & 3) + 8 * (reg >> 2) + 4 * hf;
                sm.OEp[qh2 * 32 + qr][nt * 32 + l31] = O[nt][reg];
            }
        if (lane < 32) sm.lEp[qh2 * 32 + l31] = lsum;
    }
    __syncthreads();
    if (th == 0) {
        lsum += sm.lEp[qh2 * 32 + l31];
        const float linv = 1.0f / lsum;
#pragma unroll
        for (int nt = 0; nt < 2; ++nt)
#pragma unroll
            for (int reg = 0; reg < 16; ++reg) {
                const int qr = (reg & 3) + 8 * (reg >> 2) + 4 * hf;
                const float li = __shfl(linv, qr);
                const float o =
                    O[nt][reg] + sm.OEp[qh2 * 32 + qr][nt * 32 + l31];
                aob[(size_t)(row0 + qh2 * 32 + qr) * 768 + head * 64 +
                    nt * 32 + l31] = (short)f2bf(o * li);
            }
    }
}

// ---------------------------------------------------------------------------
// proj GEMM (MFMA bf16), 64x128 tile -> 384 blocks.
// ---------------------------------------------------------------------------
__global__ __launch_bounds__(256) void proj_mfma_kernel(
    const short* __restrict__ aoh, const short* __restrict__ pwT,
    const float* __restrict__ bias, float* __restrict__ out)
{
    __shared__ __align__(16) short As[64 * 32];
    __shared__ __align__(16) short Bs[128 * 32];
    const int t = threadIdx.x;
    const int w = t >> 6, lane = t & 63;
    const int l15 = lane & 15, l4 = lane >> 4;
    const int wr = w >> 1, wc = w & 1;
    const int row0 = blockIdx.y * 64, col0 = blockIdx.x * 128;
    const int ldr = lane >> 2;
    const int ldk = (lane & 3) * 8;

    f4v acc[2][4] = {};
    const short* aBase = aoh + (size_t)(row0 + w * 16 + ldr) * 768 + ldk;
    const short* bBase = pwT + (size_t)(col0 + w * 32 + ldr) * 768 + ldk;

    for (int kk = 0; kk < 768; kk += 32) {
        __syncthreads();
        gload_lds16(aBase + kk, &As[(w * 16) * 32]);
#pragma unroll
        for (int c = 0; c < 2; ++c)
            gload_lds16(bBase + (size_t)c * 16 * 768 + kk,
                        &Bs[(w * 32 + c * 16) * 32]);
        __syncthreads();
        bf8v af[2], bg[4];
#pragma unroll
        for (int i = 0; i < 2; ++i)
            af[i] = *(const bf8v*)&As[(wr * 32 + 16 * i + l15) * 32 + l4 * 8];
#pragma unroll
        for (int j = 0; j < 4; ++j)
            bg[j] = *(const bf8v*)&Bs[(wc * 64 + 16 * j + l15) * 32 + l4 * 8];
#pragma unroll
        for (int i = 0; i < 2; ++i)
#pragma unroll
            for (int j = 0; j < 4; ++j)
                acc[i][j] = __builtin_amdgcn_mfma_f32_16x16x32_bf16(
                    af[i], bg[j], acc[i][j], 0, 0, 0);
    }

#pragma unroll
    for (int j = 0; j < 4; ++j) {
        const int n = col0 + wc * 64 + 16 * j + l15;
        const float bv = bias[n];
#pragma unroll
        for (int i = 0; i < 2; ++i) {
            const int m = row0 + wr * 32 + 16 * i + l4 * 4;
#pragma unroll
            for (int r = 0; r < 4; ++r)
                out[(size_t)(m + r) * 768 + n] = acc[i][j][r] + bv;
        }
    }
}

// ---------------------------------------------------------------------------
extern "C" void kernel_launch(void* const* d_in, const int* in_sizes, int n_in,
                              void* d_out, int out_size, void* d_ws,
                              size_t ws_size, hipStream_t stream)
{
    (void)in_sizes; (void)n_in; (void)out_size; (void)ws_size;
    const float* x    = (const float*)d_in[0];
    const float* qkvw = (const float*)d_in[1];
    const float* qkvb = (const float*)d_in[2];
    const float* pw   = (const float*)d_in[3];
    const float* pb   = (const float*)d_in[4];
    const float* rph  = (const float*)d_in[5];
    const float* rpw  = (const float*)d_in[6];
    float* out = (float*)d_out;

    const size_t S = (size_t)NHEADS * NTOK * 64;  // 3,145,728 (= 4096*768)
    short* qbh  = (short*)d_ws;          // S bf16   q  [h][tok][d]
    short* kbh  = qbh + S;               // S bf16   k  [h][tok][d]
    short* vblk = kbh + S;               // S bf16   v  [h][tok/16][d][tok%16]
    short* xh   = vblk + S;              // S bf16   x [tok][c]; dead after
    short* aob  = xh;                    //   qkv -> aliased as attn out
    short* wqkvT = xh + S;               // 2304*768 bf16
    short* pwT  = wqkvT + (size_t)2304 * 768;  // 768*768 bf16
    // total ~29.6 MB

    prep_kernel<<<dim3(2112), 256, 0, stream>>>(x, qkvw, pw, xh, wqkvT, pwT);
    qkv_mfma_kernel<<<dim3(24, 32), 256, 0, stream>>>(xh, wqkvT, qkvb,
                                                      qbh, kbh, vblk);
    flash_mfma_kernel<<<dim3(64, NHEADS), 256, 0, stream>>>(qbh, kbh, vblk,
                                                            rpw, rph, aob);
    proj_mfma_kernel<<<dim3(6, 64), 256, 0, stream>>>(aob, pwT, pb, out);
}